// Round 1
// baseline (495.715 us; speedup 1.0000x reference)
//
#include <hip/hip_runtime.h>
#include <math.h>

#define BB 4
#define NN 4096
#define KNBR 20
#define BN (BB * NN)

__device__ __forceinline__ float gelu_f(float x) {
    return 0.5f * x * (1.0f + erff(x * 0.70710678118654752440f));
}

__device__ __forceinline__ float wave_sum(float v) {
    #pragma unroll
    for (int off = 32; off > 0; off >>= 1) v += __shfl_down(v, off);
    return v;
}

// ---------------- K0: per-point precompute: q, k, packed (x,y,z,|p|^2) ----
__global__ void k0_prep(const float* __restrict__ xyz,
                        const float* __restrict__ w_q, const float* __restrict__ g_q, const float* __restrict__ b_q,
                        const float* __restrict__ w_k, const float* __restrict__ g_k, const float* __restrict__ b_k,
                        float* __restrict__ qv, float* __restrict__ kv, float4* __restrict__ pts4) {
    int t = blockIdx.x * blockDim.x + threadIdx.x;
    if (t >= BN) return;
    int b = t / NN, n = t % NN;
    const float* base = xyz + (size_t)b * 3 * NN;
    float x = base[n], y = base[NN + n], z = base[2 * NN + n];
    float sq = x * x + y * y + z * z;
    const float invs = rsqrtf(1.0f + 1e-5f);
    float qr = x * (w_q[0] + w_q[3]) + y * (w_q[1] + w_q[4]) + z * (w_q[2] + w_q[5]);
    float kr = x * (w_k[0] + w_k[3]) + y * (w_k[1] + w_k[4]) + z * (w_k[2] + w_k[5]);
    qv[t] = qr * (g_q[0] * invs) + b_q[0];
    kv[t] = kr * (g_k[0] * invs) + b_k[0];
    pts4[t] = make_float4(x, y, z, sq);
}

// ---------------- K1: kd[row] = sum_m exp(-50*dist)  (row pass) -----------
__global__ void k1_kd(const float4* __restrict__ pts4, float* __restrict__ kd) {
    int wave = threadIdx.x >> 6, lane = threadIdx.x & 63;
    int row = blockIdx.x * 4 + wave;
    int b = row / NN;
    const float4* p = pts4 + (size_t)b * NN;
    float4 fr = pts4[row];
    float acc = 0.f;
    for (int i = 0; i < NN / 64; ++i) {
        int m = i * 64 + lane;
        float4 fc = p[m];
        float dot = fr.x * fc.x + fr.y * fc.y + fr.z * fc.z;
        float d = (-2.0f * dot + fr.w) + fc.w;
        acc += expf(-50.0f * d);
    }
    acc = wave_sum(acc);
    if (lane == 0) kd[row] = acc;
}

// ---------------- K2: per-batch max(kd) -> radius -------------------------
__global__ void k2_radius(const float* __restrict__ kd, float* __restrict__ radius) {
    int b = blockIdx.x;
    __shared__ float red[1024];
    int t = threadIdx.x;
    float mx = -1e30f;
    for (int n = t; n < NN; n += 1024) mx = fmaxf(mx, kd[b * NN + n]);
    red[t] = mx;
    __syncthreads();
    for (int s = 512; s > 0; s >>= 1) {
        if (t < s) red[t] = fmaxf(red[t], red[t + s]);
        __syncthreads();
    }
    float kmax = red[0];
    for (int n = t; n < NN; n += 1024) {
        float sc = kd[b * NN + n] / (kmax + 1e-9f);
        radius[b * NN + n] = 0.1f + 0.1f * sc;
    }
}

// ---------------- K3: Z[row] = sum_{kept m} exp(q_n k_m)  (row pass) ------
__global__ void k3_Z(const float4* __restrict__ pts4, const float* __restrict__ qv,
                     const float* __restrict__ kv, const float* __restrict__ radius,
                     float* __restrict__ Z) {
    int wave = threadIdx.x >> 6, lane = threadIdx.x & 63;
    int row = blockIdx.x * 4 + wave;
    int b = row / NN;
    const float4* p = pts4 + (size_t)b * NN;
    const float* kb = kv + (size_t)b * NN;
    float4 fr = pts4[row];
    float qn = qv[row], rad = radius[row];
    float acc = 0.f;
    for (int i = 0; i < NN / 64; ++i) {
        int m = i * 64 + lane;
        float4 fc = p[m];
        float dot = fr.x * fc.x + fr.y * fc.y + fr.z * fc.z;
        float d = (-2.0f * dot + fr.w) + fc.w;
        float e = expf(qn * kb[m]);
        acc += (d < rad) ? e : 0.0f;
    }
    acc = wave_sum(acc);
    if (lane == 0) Z[row] = acc;
}

// ---------------- K4: colsum[m] = sum_{n: kept(n,m)} exp(q_n k_m)/Z_n -----
__global__ void k4_colsum(const float4* __restrict__ pts4, const float* __restrict__ qv,
                          const float* __restrict__ kv, const float* __restrict__ radius,
                          const float* __restrict__ Z, float* __restrict__ colsum) {
    int wave = threadIdx.x >> 6, lane = threadIdx.x & 63;
    int col = blockIdx.x * 4 + wave;
    int b = col / NN;
    const float4* p = pts4 + (size_t)b * NN;
    const float* qb = qv + (size_t)b * NN;
    const float* rb = radius + (size_t)b * NN;
    const float* Zb = Z + (size_t)b * NN;
    float4 fcc = pts4[col];
    float km = kv[col];
    float acc = 0.f;
    for (int i = 0; i < NN / 64; ++i) {
        int n = i * 64 + lane;
        float4 fr = p[n];   // row point (n)
        float dot = fr.x * fcc.x + fr.y * fcc.y + fr.z * fcc.z;
        float d = (-2.0f * dot + fr.w) + fcc.w;   // sq_row first (matches ref)
        float e = expf(qb[n] * km) / Zb[n];
        acc += (d < rb[n]) ? e : 0.0f;
    }
    acc = wave_sum(acc);
    if (lane == 0) colsum[col] = fmaxf(acc, 1e-12f);
}

// ---------------- K5: rs[n] = max( (sum_{kept m} exp(q k)/colsum_m)/Z_n, 1e-12 )
__global__ void k5_rs(const float4* __restrict__ pts4, const float* __restrict__ qv,
                      const float* __restrict__ kv, const float* __restrict__ radius,
                      const float* __restrict__ Z, const float* __restrict__ colsum,
                      float* __restrict__ rs) {
    int wave = threadIdx.x >> 6, lane = threadIdx.x & 63;
    int row = blockIdx.x * 4 + wave;
    int b = row / NN;
    const float4* p = pts4 + (size_t)b * NN;
    const float* kb = kv + (size_t)b * NN;
    const float* cb = colsum + (size_t)b * NN;
    float4 fr = pts4[row];
    float qn = qv[row], rad = radius[row], Zn = Z[row];
    float acc = 0.f;
    for (int i = 0; i < NN / 64; ++i) {
        int m = i * 64 + lane;
        float4 fc = p[m];
        float dot = fr.x * fc.x + fr.y * fc.y + fr.z * fc.z;
        float d = (-2.0f * dot + fr.w) + fc.w;
        float e = expf(qn * kb[m]) / cb[m];
        acc += (d < rad) ? e : 0.0f;
    }
    acc = wave_sum(acc);
    if (lane == 0) rs[row] = fmaxf(acc / Zn, 1e-12f);
}

// ---------------- K6: smoothed[c,m] = (1/colsum_m) sum_n x_cn exp(qk)/(Z_n rs_n)
__global__ void k6_smooth(const float4* __restrict__ pts4, const float* __restrict__ qv,
                          const float* __restrict__ kv, const float* __restrict__ radius,
                          const float* __restrict__ Z, const float* __restrict__ rs,
                          const float* __restrict__ colsum, float* __restrict__ smoothed) {
    int wave = threadIdx.x >> 6, lane = threadIdx.x & 63;
    int col = blockIdx.x * 4 + wave;
    int b = col / NN, nloc = col % NN;
    const float4* p = pts4 + (size_t)b * NN;
    const float* qb = qv + (size_t)b * NN;
    const float* rb = radius + (size_t)b * NN;
    const float* Zb = Z + (size_t)b * NN;
    const float* sb = rs + (size_t)b * NN;
    float4 fcc = pts4[col];
    float km = kv[col];
    float ax = 0.f, ay = 0.f, az = 0.f;
    for (int i = 0; i < NN / 64; ++i) {
        int n = i * 64 + lane;
        float4 fr = p[n];
        float dot = fr.x * fcc.x + fr.y * fcc.y + fr.z * fcc.z;
        float d = (-2.0f * dot + fr.w) + fcc.w;
        float w = expf(qb[n] * km) / (Zb[n] * sb[n]);
        w = (d < rb[n]) ? w : 0.0f;
        ax += fr.x * w;
        ay += fr.y * w;
        az += fr.z * w;
    }
    ax = wave_sum(ax);
    ay = wave_sum(ay);
    az = wave_sum(az);
    if (lane == 0) {
        float inv = 1.0f / colsum[col];
        float* out = smoothed + (size_t)b * 3 * NN + nloc;
        out[0] = ax * inv;
        out[NN] = ay * inv;
        out[2 * NN] = az * inv;
    }
}

// ---------------- K7: first-20-by-index in-ball neighbors (dist <= radius)
__global__ void k7_pe_idx(const float4* __restrict__ pts4, const float* __restrict__ radius,
                          int* __restrict__ idxg) {
    int wave = threadIdx.x >> 6, lane = threadIdx.x & 63;
    int row = blockIdx.x * 4 + wave;
    int b = row / NN;
    const float4* p = pts4 + (size_t)b * NN;
    float4 fr = pts4[row];
    float rad = radius[row];
    int total = 0;
    int firstm = 0;
    bool have = false;
    unsigned long long lmask = (1ULL << lane) - 1ULL;
    for (int i = 0; i < NN / 64 && total < KNBR; ++i) {
        int m = i * 64 + lane;
        float4 fc = p[m];
        float dot = fr.x * fc.x + fr.y * fc.y + fr.z * fc.z;
        float d = (-2.0f * dot + fr.w) + fc.w;
        bool inb = !(d > rad);   // dist <= radius (non-strict, per reference)
        unsigned long long mask = __ballot(inb);
        if (!have && mask != 0ULL) {
            int src = __ffsll(mask) - 1;
            firstm = __shfl(m, src);
            have = true;
        }
        int pos = total + (int)__popcll(mask & lmask);
        if (inb && pos < KNBR) idxg[(size_t)row * KNBR + pos] = m;
        total += (int)__popcll(mask);
    }
    if (total < KNBR && lane >= total && lane < KNBR)
        idxg[(size_t)row * KNBR + lane] = firstm;
}

// ---------------- K8: fused per-point epilogue ----------------------------
__global__ void k8_final(const float* __restrict__ xyz, const float* __restrict__ smoothed,
                         const int* __restrict__ idxg,
                         const float* __restrict__ w_v, const float* __restrict__ g_v, const float* __restrict__ b_v,
                         const float* __restrict__ w_pe, const float* __restrict__ b_pe,
                         const float* __restrict__ g_pe, const float* __restrict__ bb_pe,
                         const float* __restrict__ w_m1, const float* __restrict__ g_m1, const float* __restrict__ b_m1,
                         const float* __restrict__ w_m2, const float* __restrict__ g_m2, const float* __restrict__ b_m2,
                         const float* __restrict__ w_out, const float* __restrict__ g_out, const float* __restrict__ b_out,
                         float* __restrict__ out) {
    int t = blockIdx.x * blockDim.x + threadIdx.x;
    if (t >= BN) return;
    int b = t / NN, n = t % NN;
    const float* xb = xyz + (size_t)b * 3 * NN;
    float x = xb[n], y = xb[NN + n], z = xb[2 * NN + n];
    const float* sb = smoothed + (size_t)b * 3 * NN;
    float vx = sb[n] - x, vy = sb[NN + n] - y, vz = sb[2 * NN + n] - z;
    const float invs = rsqrtf(1.0f + 1e-5f);

    // --- position encoder: 9 -> 8, gelu(bn), max over K neighbors ---
    float pf8[8];
    #pragma unroll
    for (int o = 0; o < 8; ++o) pf8[o] = -1e30f;
    for (int kk = 0; kk < KNBR; ++kk) {
        int j = idxg[(size_t)t * KNBR + kk];
        float gx = xb[j], gy = xb[NN + j], gz = xb[2 * NN + j];
        float dx = gx - x, dy = gy - y, dz = gz - z;
        #pragma unroll
        for (int o = 0; o < 8; ++o) {
            const float* w = w_pe + o * 9;
            float s = w[0] * x + w[1] * y + w[2] * z + w[3] * gx + w[4] * gy + w[5] * gz
                    + w[6] * dx + w[7] * dy + w[8] * dz + b_pe[o];
            s = s * (g_pe[o] * invs) + bb_pe[o];
            s = gelu_f(s);
            pf8[o] = fmaxf(pf8[o], s);
        }
    }
    // --- m1: 8 -> 16, gelu(bn) ---
    float pf16[16];
    #pragma unroll
    for (int o = 0; o < 16; ++o) {
        const float* w = w_m1 + o * 8;
        float s = 0.f;
        #pragma unroll
        for (int c = 0; c < 8; ++c) s += w[c] * pf8[c];
        pf16[o] = gelu_f(s * (g_m1[o] * invs) + b_m1[o]);
    }
    // --- m2 (16->64) + value conv (6->64), gelu(v + pos) ---
    float g64[64];
    #pragma unroll
    for (int o = 0; o < 64; ++o) {
        const float* wm = w_m2 + o * 16;
        float pos = 0.f;
        #pragma unroll
        for (int c = 0; c < 16; ++c) pos += wm[c] * pf16[c];
        pos = pos * (g_m2[o] * invs) + b_m2[o];
        const float* wv = w_v + o * 6;
        float vv = wv[0] * vx + wv[1] * vy + wv[2] * vz + wv[3] * x + wv[4] * y + wv[5] * z;
        vv = vv * (g_v[o] * invs) + b_v[o];
        g64[o] = gelu_f(vv + pos);
    }
    // --- out conv 64 -> 32 + BN ---
    #pragma unroll
    for (int o = 0; o < 32; ++o) {
        const float* w = w_out + o * 64;
        float s = 0.f;
        #pragma unroll
        for (int c = 0; c < 64; ++c) s += w[c] * g64[c];
        out[((size_t)b * 32 + o) * NN + n] = s * (g_out[o] * invs) + b_out[o];
    }
}

extern "C" void kernel_launch(void* const* d_in, const int* in_sizes, int n_in,
                              void* d_out, int out_size, void* d_ws, size_t ws_size,
                              hipStream_t stream) {
    const float* xyz  = (const float*)d_in[0];
    const float* w_q  = (const float*)d_in[1];
    const float* g_q  = (const float*)d_in[2];
    const float* b_q  = (const float*)d_in[3];
    const float* w_k  = (const float*)d_in[4];
    const float* g_k  = (const float*)d_in[5];
    const float* b_k  = (const float*)d_in[6];
    const float* w_v  = (const float*)d_in[7];
    const float* g_v  = (const float*)d_in[8];
    const float* b_v  = (const float*)d_in[9];
    const float* w_pe = (const float*)d_in[10];
    const float* b_pe = (const float*)d_in[11];
    const float* g_pe = (const float*)d_in[12];
    const float* bb_pe= (const float*)d_in[13];
    const float* w_m1 = (const float*)d_in[14];
    const float* g_m1 = (const float*)d_in[15];
    const float* b_m1 = (const float*)d_in[16];
    const float* w_m2 = (const float*)d_in[17];
    const float* g_m2 = (const float*)d_in[18];
    const float* b_m2 = (const float*)d_in[19];
    const float* w_out= (const float*)d_in[20];
    const float* g_out= (const float*)d_in[21];
    const float* b_out= (const float*)d_in[22];

    float* ws = (float*)d_ws;
    float*  qv       = ws;
    float*  kv       = ws + (size_t)BN;
    float4* pts4     = (float4*)(ws + (size_t)2 * BN);   // 4*BN floats
    float*  kd       = ws + (size_t)6 * BN;
    float*  radius   = ws + (size_t)7 * BN;
    float*  Zv       = ws + (size_t)8 * BN;
    float*  colsum   = ws + (size_t)9 * BN;
    float*  rsv      = ws + (size_t)10 * BN;
    float*  smoothed = ws + (size_t)11 * BN;             // 3*BN floats
    int*    idxg     = (int*)(ws + (size_t)14 * BN);     // BN*20 ints

    k0_prep<<<BN / 256, 256, 0, stream>>>(xyz, w_q, g_q, b_q, w_k, g_k, b_k, qv, kv, pts4);
    k1_kd<<<BN / 4, 256, 0, stream>>>(pts4, kd);
    k2_radius<<<BB, 1024, 0, stream>>>(kd, radius);
    k3_Z<<<BN / 4, 256, 0, stream>>>(pts4, qv, kv, radius, Zv);
    k4_colsum<<<BN / 4, 256, 0, stream>>>(pts4, qv, kv, radius, Zv, colsum);
    k5_rs<<<BN / 4, 256, 0, stream>>>(pts4, qv, kv, radius, Zv, colsum, rsv);
    k6_smooth<<<BN / 4, 256, 0, stream>>>(pts4, qv, kv, radius, Zv, rsv, colsum, smoothed);
    k7_pe_idx<<<BN / 4, 256, 0, stream>>>(pts4, radius, idxg);
    k8_final<<<BN / 256, 256, 0, stream>>>(xyz, smoothed, idxg,
                                           w_v, g_v, b_v,
                                           w_pe, b_pe, g_pe, bb_pe,
                                           w_m1, g_m1, b_m1,
                                           w_m2, g_m2, b_m2,
                                           w_out, g_out, b_out,
                                           (float*)d_out);
}

// Round 2
// 305.802 us; speedup vs baseline: 1.6210x; 1.6210x over previous
//
#include <hip/hip_runtime.h>
#include <math.h>

#define BB 4
#define NN 4096
#define KNBR 20
#define BN (BB * NN)
#define CHUNKS 16
#define CLEN (NN / CHUNKS)   // 256

__device__ __forceinline__ float gelu_f(float x) {
    return 0.5f * x * (1.0f + erff(x * 0.70710678118654752440f));
}

// ---------------- K0: per-point precompute: q, k, packed (x,y,z,|p|^2) ----
__global__ void k0_prep(const float* __restrict__ xyz,
                        const float* __restrict__ w_q, const float* __restrict__ g_q, const float* __restrict__ b_q,
                        const float* __restrict__ w_k, const float* __restrict__ g_k, const float* __restrict__ b_k,
                        float* __restrict__ qv, float* __restrict__ kv, float4* __restrict__ pts4) {
    int t = blockIdx.x * blockDim.x + threadIdx.x;
    if (t >= BN) return;
    int b = t / NN, n = t % NN;
    const float* base = xyz + (size_t)b * 3 * NN;
    float x = base[n], y = base[NN + n], z = base[2 * NN + n];
    float sq = x * x + y * y + z * z;
    const float invs = rsqrtf(1.0f + 1e-5f);
    float qr = x * (w_q[0] + w_q[3]) + y * (w_q[1] + w_q[4]) + z * (w_q[2] + w_q[5]);
    float kr = x * (w_k[0] + w_k[3]) + y * (w_k[1] + w_k[4]) + z * (w_k[2] + w_k[5]);
    qv[t] = qr * (g_q[0] * invs) + b_q[0];
    kv[t] = kr * (g_k[0] * invs) + b_k[0];
    pts4[t] = make_float4(x, y, z, sq);
}

// Common wave decomposition for pair passes:
//   wave W (uniform via readfirstlane): og = W>>4 (64-output group), chunk = W&15
//   lane = output index within group; loop over summed dim, uniform index.

// ---------------- P1: kd partials (row pass) ------------------------------
__global__ void p1_kd(const float4* __restrict__ pts4, float* __restrict__ part) {
    int W = __builtin_amdgcn_readfirstlane((blockIdx.x * blockDim.x + threadIdx.x) >> 6);
    int lane = threadIdx.x & 63;
    int og = W >> 4, chunk = W & (CHUNKS - 1);
    int row = og * 64 + lane;
    int b = og / (NN / 64);
    const float4* p = pts4 + (size_t)b * NN;
    float4 fr = pts4[row];
    float acc = 0.f;
    int i0 = chunk * CLEN;
    #pragma unroll 4
    for (int i = i0; i < i0 + CLEN; ++i) {
        float4 fc = p[i];
        float dot = fr.x * fc.x + fr.y * fc.y + fr.z * fc.z;
        float d = fmaf(-2.0f, dot, fr.w) + fc.w;
        acc += __expf(-50.0f * d);
    }
    part[chunk * BN + row] = acc;
}

// ---------------- R1: reduce kd -------------------------------------------
__global__ void r1_kd(const float* __restrict__ part, float* __restrict__ kd) {
    int t = blockIdx.x * blockDim.x + threadIdx.x;
    float s = 0.f;
    #pragma unroll
    for (int c = 0; c < CHUNKS; ++c) s += part[c * BN + t];
    kd[t] = s;
}

// ---------------- K2: per-batch max(kd) -> radius -------------------------
__global__ void k2_radius(const float* __restrict__ kd, float* __restrict__ radius) {
    int b = blockIdx.x;
    __shared__ float red[1024];
    int t = threadIdx.x;
    float mx = -1e30f;
    for (int n = t; n < NN; n += 1024) mx = fmaxf(mx, kd[b * NN + n]);
    red[t] = mx;
    __syncthreads();
    for (int s = 512; s > 0; s >>= 1) {
        if (t < s) red[t] = fmaxf(red[t], red[t + s]);
        __syncthreads();
    }
    float kmax = red[0];
    for (int n = t; n < NN; n += 1024) {
        float sc = kd[b * NN + n] / (kmax + 1e-9f);
        radius[b * NN + n] = 0.1f + 0.1f * sc;
    }
}

// ---------------- P3: Z partials (row pass) -------------------------------
__global__ void p3_Z(const float4* __restrict__ pts4, const float* __restrict__ qv,
                     const float* __restrict__ kv, const float* __restrict__ radius,
                     float* __restrict__ part) {
    int W = __builtin_amdgcn_readfirstlane((blockIdx.x * blockDim.x + threadIdx.x) >> 6);
    int lane = threadIdx.x & 63;
    int og = W >> 4, chunk = W & (CHUNKS - 1);
    int row = og * 64 + lane;
    int b = og / (NN / 64);
    const float4* p = pts4 + (size_t)b * NN;
    const float* kb = kv + (size_t)b * NN;
    float4 fr = pts4[row];
    float qn = qv[row], rad = radius[row];
    float acc = 0.f;
    int i0 = chunk * CLEN;
    #pragma unroll 4
    for (int i = i0; i < i0 + CLEN; ++i) {
        float4 fc = p[i];
        float dot = fr.x * fc.x + fr.y * fc.y + fr.z * fc.z;
        float d = fmaf(-2.0f, dot, fr.w) + fc.w;
        float e = __expf(qn * kb[i]);
        acc += (d < rad) ? e : 0.f;
    }
    part[chunk * BN + row] = acc;
}

// ---------------- R3: reduce Z; build aux_a = {q, rad, lnZ, _} ------------
__global__ void r3_Z(const float* __restrict__ part, const float* __restrict__ qv,
                     const float* __restrict__ radius, float* __restrict__ Z,
                     float4* __restrict__ aux_a) {
    int t = blockIdx.x * blockDim.x + threadIdx.x;
    float s = 0.f;
    #pragma unroll
    for (int c = 0; c < CHUNKS; ++c) s += part[c * BN + t];
    Z[t] = s;
    aux_a[t] = make_float4(qv[t], radius[t], __logf(s), 0.f);
}

// ---------------- P4: colsum partials (col pass) --------------------------
__global__ void p4_colsum(const float4* __restrict__ pts4, const float4* __restrict__ aux_a,
                          const float* __restrict__ kv, float* __restrict__ part) {
    int W = __builtin_amdgcn_readfirstlane((blockIdx.x * blockDim.x + threadIdx.x) >> 6);
    int lane = threadIdx.x & 63;
    int og = W >> 4, chunk = W & (CHUNKS - 1);
    int col = og * 64 + lane;
    int b = og / (NN / 64);
    const float4* p = pts4 + (size_t)b * NN;
    const float4* a = aux_a + (size_t)b * NN;
    float4 fcc = pts4[col];
    float km = kv[col];
    float acc = 0.f;
    int i0 = chunk * CLEN;
    #pragma unroll 4
    for (int i = i0; i < i0 + CLEN; ++i) {
        float4 fr = p[i];            // row point n (uniform)
        float4 an = a[i];            // {q_n, rad_n, lnZ_n, _}
        float dot = fr.x * fcc.x + fr.y * fcc.y + fr.z * fcc.z;
        float d = fmaf(-2.0f, dot, fr.w) + fcc.w;
        float e = __expf(an.x * km - an.z);   // exp(q_n k_m)/Z_n
        acc += (d < an.y) ? e : 0.f;
    }
    part[chunk * BN + col] = acc;
}

// ---------------- R4: reduce colsum; kc2 = {k, ln(colsum)} ----------------
__global__ void r4_colsum(const float* __restrict__ part, const float* __restrict__ kv,
                          float* __restrict__ colsum, float2* __restrict__ kc2) {
    int t = blockIdx.x * blockDim.x + threadIdx.x;
    float s = 0.f;
    #pragma unroll
    for (int c = 0; c < CHUNKS; ++c) s += part[c * BN + t];
    s = fmaxf(s, 1e-12f);
    colsum[t] = s;
    kc2[t] = make_float2(kv[t], __logf(s));
}

// ---------------- P5: rs partials (row pass) ------------------------------
__global__ void p5_rs(const float4* __restrict__ pts4, const float* __restrict__ qv,
                      const float* __restrict__ radius, const float2* __restrict__ kc2,
                      float* __restrict__ part) {
    int W = __builtin_amdgcn_readfirstlane((blockIdx.x * blockDim.x + threadIdx.x) >> 6);
    int lane = threadIdx.x & 63;
    int og = W >> 4, chunk = W & (CHUNKS - 1);
    int row = og * 64 + lane;
    int b = og / (NN / 64);
    const float4* p = pts4 + (size_t)b * NN;
    const float2* kc = kc2 + (size_t)b * NN;
    float4 fr = pts4[row];
    float qn = qv[row], rad = radius[row];
    float acc = 0.f;
    int i0 = chunk * CLEN;
    #pragma unroll 4
    for (int i = i0; i < i0 + CLEN; ++i) {
        float4 fc = p[i];
        float2 km = kc[i];           // {k_m, ln colsum_m}
        float dot = fr.x * fc.x + fr.y * fc.y + fr.z * fc.z;
        float d = fmaf(-2.0f, dot, fr.w) + fc.w;
        float e = __expf(qn * km.x - km.y);   // exp(qk)/colsum_m
        acc += (d < rad) ? e : 0.f;
    }
    part[chunk * BN + row] = acc;
}

// ---------------- R5: rs = max(acc/Z,1e-12); aux_a.w = lnZ + ln rs --------
__global__ void r5_rs(const float* __restrict__ part, const float* __restrict__ Z,
                      float4* __restrict__ aux_a) {
    int t = blockIdx.x * blockDim.x + threadIdx.x;
    float s = 0.f;
    #pragma unroll
    for (int c = 0; c < CHUNKS; ++c) s += part[c * BN + t];
    float rs = fmaxf(s / Z[t], 1e-12f);
    float4 a = aux_a[t];
    a.w = a.z + __logf(rs);
    aux_a[t] = a;
}

// ---------------- P6: smoothed partials (col pass, 3 accs) ----------------
__global__ void p6_smooth(const float4* __restrict__ pts4, const float4* __restrict__ aux_a,
                          const float* __restrict__ kv, float* __restrict__ partx,
                          float* __restrict__ party, float* __restrict__ partz) {
    int W = __builtin_amdgcn_readfirstlane((blockIdx.x * blockDim.x + threadIdx.x) >> 6);
    int lane = threadIdx.x & 63;
    int og = W >> 4, chunk = W & (CHUNKS - 1);
    int col = og * 64 + lane;
    int b = og / (NN / 64);
    const float4* p = pts4 + (size_t)b * NN;
    const float4* a = aux_a + (size_t)b * NN;
    float4 fcc = pts4[col];
    float km = kv[col];
    float ax = 0.f, ay = 0.f, az = 0.f;
    int i0 = chunk * CLEN;
    #pragma unroll 4
    for (int i = i0; i < i0 + CLEN; ++i) {
        float4 fr = p[i];
        float4 an = a[i];            // {q_n, rad_n, lnZ_n, lnZ_n + ln rs_n}
        float dot = fr.x * fcc.x + fr.y * fcc.y + fr.z * fcc.z;
        float d = fmaf(-2.0f, dot, fr.w) + fcc.w;
        float w = __expf(an.x * km - an.w);    // exp(qk)/(Z_n rs_n)
        w = (d < an.y) ? w : 0.f;
        ax += fr.x * w;
        ay += fr.y * w;
        az += fr.z * w;
    }
    partx[chunk * BN + col] = ax;
    party[chunk * BN + col] = ay;
    partz[chunk * BN + col] = az;
}

// ---------------- R6: reduce + /colsum -> smoothed [B,3,N] ----------------
__global__ void r6_smooth(const float* __restrict__ partx, const float* __restrict__ party,
                          const float* __restrict__ partz, const float* __restrict__ colsum,
                          float* __restrict__ smoothed) {
    int t = blockIdx.x * blockDim.x + threadIdx.x;
    int b = t / NN, n = t % NN;
    float sx = 0.f, sy = 0.f, sz = 0.f;
    #pragma unroll
    for (int c = 0; c < CHUNKS; ++c) {
        sx += partx[c * BN + t];
        sy += party[c * BN + t];
        sz += partz[c * BN + t];
    }
    float inv = 1.0f / colsum[t];
    float* o = smoothed + (size_t)b * 3 * NN + n;
    o[0] = sx * inv;
    o[NN] = sy * inv;
    o[2 * NN] = sz * inv;
}

// ---------------- K7: first-20-by-index in-ball neighbors -----------------
__global__ void k7_pe_idx(const float4* __restrict__ pts4, const float* __restrict__ radius,
                          int* __restrict__ idxg) {
    int wave = threadIdx.x >> 6, lane = threadIdx.x & 63;
    int row = blockIdx.x * 4 + wave;
    int b = row / NN;
    const float4* p = pts4 + (size_t)b * NN;
    float4 fr = pts4[row];
    float rad = radius[row];
    int total = 0;
    int firstm = 0;
    bool have = false;
    unsigned long long lmask = (1ULL << lane) - 1ULL;
    for (int i = 0; i < NN / 64 && total < KNBR; ++i) {
        int m = i * 64 + lane;
        float4 fc = p[m];
        float dot = fr.x * fc.x + fr.y * fc.y + fr.z * fc.z;
        float d = fmaf(-2.0f, dot, fr.w) + fc.w;
        bool inb = !(d > rad);   // dist <= radius
        unsigned long long mask = __ballot(inb);
        if (!have && mask != 0ULL) {
            int src = __ffsll(mask) - 1;
            firstm = __shfl(m, src);
            have = true;
        }
        int pos = total + (int)__popcll(mask & lmask);
        if (inb && pos < KNBR) idxg[(size_t)row * KNBR + pos] = m;
        total += (int)__popcll(mask);
    }
    if (total < KNBR && lane >= total && lane < KNBR)
        idxg[(size_t)row * KNBR + lane] = firstm;
}

// ---------------- K8: fused epilogue, 8 threads per point ----------------
__global__ void k8_final(const float* __restrict__ xyz, const float* __restrict__ smoothed,
                         const int* __restrict__ idxg,
                         const float* __restrict__ w_v, const float* __restrict__ g_v, const float* __restrict__ b_v,
                         const float* __restrict__ w_pe, const float* __restrict__ b_pe,
                         const float* __restrict__ g_pe, const float* __restrict__ bb_pe,
                         const float* __restrict__ w_m1, const float* __restrict__ g_m1, const float* __restrict__ b_m1,
                         const float* __restrict__ w_m2, const float* __restrict__ g_m2, const float* __restrict__ b_m2,
                         const float* __restrict__ w_out, const float* __restrict__ g_out, const float* __restrict__ b_out,
                         float* __restrict__ out) {
    __shared__ float s_pf8[32][9];    // +1 pad
    __shared__ float s_pf16[32][17];  // +1 pad
    __shared__ float s_g64[32][65];   // +1 pad
    int tid = threadIdx.x;
    int ptL = tid >> 3, o = tid & 7;
    int p = blockIdx.x * 32 + ptL;
    int b = p / NN, n = p % NN;
    const float* xb = xyz + (size_t)b * 3 * NN;
    float x = xb[n], y = xb[NN + n], z = xb[2 * NN + n];
    const float invs = rsqrtf(1.0f + 1e-5f);

    // --- phase A: PE 9->8, gelu(bn), max over K; thread = channel o ---
    float w0 = w_pe[o * 9 + 0], w1 = w_pe[o * 9 + 1], w2 = w_pe[o * 9 + 2];
    float w3 = w_pe[o * 9 + 3], w4 = w_pe[o * 9 + 4], w5 = w_pe[o * 9 + 5];
    float w6 = w_pe[o * 9 + 6], w7 = w_pe[o * 9 + 7], w8 = w_pe[o * 9 + 8];
    float bp = b_pe[o], gp = g_pe[o] * invs, bbp = bb_pe[o];
    float mx = -1e30f;
    for (int kk = 0; kk < KNBR; ++kk) {
        int j = idxg[(size_t)p * KNBR + kk];
        float gx = xb[j], gy = xb[NN + j], gz = xb[2 * NN + j];
        float dx = gx - x, dy = gy - y, dz = gz - z;
        float s = w0 * x + w1 * y + w2 * z + w3 * gx + w4 * gy + w5 * gz
                + w6 * dx + w7 * dy + w8 * dz + bp;
        s = gelu_f(s * gp + bbp);
        mx = fmaxf(mx, s);
    }
    s_pf8[ptL][o] = mx;
    __syncthreads();

    // --- phase B: m1 8->16, outputs o and o+8 ---
    #pragma unroll
    for (int rr = 0; rr < 2; ++rr) {
        int r = o + rr * 8;
        const float* w = w_m1 + r * 8;
        float s = 0.f;
        #pragma unroll
        for (int c = 0; c < 8; ++c) s += w[c] * s_pf8[ptL][c];
        s_pf16[ptL][r] = gelu_f(s * (g_m1[r] * invs) + b_m1[r]);
    }
    __syncthreads();

    // --- phase C: m2 16->64 + value conv, gelu(v+pos); channels o*8..o*8+7
    const float* sb = smoothed + (size_t)b * 3 * NN;
    float vx = sb[n] - x, vy = sb[NN + n] - y, vz = sb[2 * NN + n] - z;
    #pragma unroll
    for (int i = 0; i < 8; ++i) {
        int ch = o * 8 + i;
        const float* wm = w_m2 + ch * 16;
        float pos = 0.f;
        #pragma unroll
        for (int c = 0; c < 16; ++c) pos += wm[c] * s_pf16[ptL][c];
        pos = pos * (g_m2[ch] * invs) + b_m2[ch];
        const float* wv = w_v + ch * 6;
        float vv = wv[0] * vx + wv[1] * vy + wv[2] * vz + wv[3] * x + wv[4] * y + wv[5] * z;
        vv = vv * (g_v[ch] * invs) + b_v[ch];
        s_g64[ptL][ch] = gelu_f(vv + pos);
    }
    __syncthreads();

    // --- phase D: out conv 64->32 + BN; outputs o*4..o*4+3 ---
    #pragma unroll
    for (int i = 0; i < 4; ++i) {
        int ch = o * 4 + i;
        const float* w = w_out + ch * 64;
        float s = 0.f;
        #pragma unroll
        for (int c = 0; c < 64; ++c) s += w[c] * s_g64[ptL][c];
        out[((size_t)b * 32 + ch) * NN + n] = s * (g_out[ch] * invs) + b_out[ch];
    }
}

extern "C" void kernel_launch(void* const* d_in, const int* in_sizes, int n_in,
                              void* d_out, int out_size, void* d_ws, size_t ws_size,
                              hipStream_t stream) {
    const float* xyz  = (const float*)d_in[0];
    const float* w_q  = (const float*)d_in[1];
    const float* g_q  = (const float*)d_in[2];
    const float* b_q  = (const float*)d_in[3];
    const float* w_k  = (const float*)d_in[4];
    const float* g_k  = (const float*)d_in[5];
    const float* b_k  = (const float*)d_in[6];
    const float* w_v  = (const float*)d_in[7];
    const float* g_v  = (const float*)d_in[8];
    const float* b_v  = (const float*)d_in[9];
    const float* w_pe = (const float*)d_in[10];
    const float* b_pe = (const float*)d_in[11];
    const float* g_pe = (const float*)d_in[12];
    const float* bb_pe= (const float*)d_in[13];
    const float* w_m1 = (const float*)d_in[14];
    const float* g_m1 = (const float*)d_in[15];
    const float* b_m1 = (const float*)d_in[16];
    const float* w_m2 = (const float*)d_in[17];
    const float* g_m2 = (const float*)d_in[18];
    const float* b_m2 = (const float*)d_in[19];
    const float* w_out= (const float*)d_in[20];
    const float* g_out= (const float*)d_in[21];
    const float* b_out= (const float*)d_in[22];

    float* ws = (float*)d_ws;
    float*  qv       = ws;                               // BN
    float*  kv       = ws + (size_t)1 * BN;              // BN
    float4* pts4     = (float4*)(ws + (size_t)2 * BN);   // 4BN
    float*  kd       = ws + (size_t)6 * BN;              // BN
    float*  radius   = ws + (size_t)7 * BN;              // BN
    float*  Zv       = ws + (size_t)8 * BN;              // BN
    float*  colsum   = ws + (size_t)9 * BN;              // BN
    float4* aux_a    = (float4*)(ws + (size_t)10 * BN);  // 4BN
    float2* kc2      = (float2*)(ws + (size_t)14 * BN);  // 2BN
    float*  smoothed = ws + (size_t)16 * BN;             // 3BN
    int*    idxg     = (int*)(ws + (size_t)19 * BN);     // 20BN
    float*  part     = ws + (size_t)39 * BN;             // up to 48BN (P6: 3x16BN)
    float*  partx = part, *party = part + (size_t)CHUNKS * BN, *partz = part + (size_t)2 * CHUNKS * BN;

    const int PB = (BN / 64) * CHUNKS / 4;   // 1024 blocks of 256 (4096 waves)

    k0_prep<<<BN / 256, 256, 0, stream>>>(xyz, w_q, g_q, b_q, w_k, g_k, b_k, qv, kv, pts4);
    p1_kd<<<PB, 256, 0, stream>>>(pts4, part);
    r1_kd<<<BN / 256, 256, 0, stream>>>(part, kd);
    k2_radius<<<BB, 1024, 0, stream>>>(kd, radius);
    p3_Z<<<PB, 256, 0, stream>>>(pts4, qv, kv, radius, part);
    r3_Z<<<BN / 256, 256, 0, stream>>>(part, qv, radius, Zv, aux_a);
    p4_colsum<<<PB, 256, 0, stream>>>(pts4, aux_a, kv, part);
    r4_colsum<<<BN / 256, 256, 0, stream>>>(part, kv, colsum, kc2);
    p5_rs<<<PB, 256, 0, stream>>>(pts4, qv, radius, kc2, part);
    r5_rs<<<BN / 256, 256, 0, stream>>>(part, Zv, aux_a);
    p6_smooth<<<PB, 256, 0, stream>>>(pts4, aux_a, kv, partx, party, partz);
    r6_smooth<<<BN / 256, 256, 0, stream>>>(partx, party, partz, colsum, smoothed);
    k7_pe_idx<<<BN / 4, 256, 0, stream>>>(pts4, radius, idxg);
    k8_final<<<BN / 32, 256, 0, stream>>>(xyz, smoothed, idxg,
                                          w_v, g_v, b_v,
                                          w_pe, b_pe, g_pe, bb_pe,
                                          w_m1, g_m1, b_m1,
                                          w_m2, g_m2, b_m2,
                                          w_out, g_out, b_out,
                                          (float*)d_out);
}

// Round 3
// 277.337 us; speedup vs baseline: 1.7874x; 1.1026x over previous
//
#include <hip/hip_runtime.h>
#include <math.h>

#define BB 4
#define NN 4096
#define KNBR 20
#define BN (BB * NN)
#define HALF 2048          // rows per block-half
#define RPW 128            // rows per wave (2048/16)

__device__ __forceinline__ float gelu_f(float x) {
    return 0.5f * x * (1.0f + erff(x * 0.70710678118654752440f));
}

// ---------------- K0: per-point precompute: q, k, packed (x,y,z,|p|^2) ----
__global__ void k0_prep(const float* __restrict__ xyz,
                        const float* __restrict__ w_q, const float* __restrict__ g_q, const float* __restrict__ b_q,
                        const float* __restrict__ w_k, const float* __restrict__ g_k, const float* __restrict__ b_k,
                        float* __restrict__ qv, float* __restrict__ kv, float4* __restrict__ pts4) {
    int t = blockIdx.x * blockDim.x + threadIdx.x;
    if (t >= BN) return;
    int b = t / NN, n = t % NN;
    const float* base = xyz + (size_t)b * 3 * NN;
    float x = base[n], y = base[NN + n], z = base[2 * NN + n];
    float sq = x * x + y * y + z * z;
    const float invs = rsqrtf(1.0f + 1e-5f);
    float qr = x * (w_q[0] + w_q[3]) + y * (w_q[1] + w_q[4]) + z * (w_q[2] + w_q[5]);
    float kr = x * (w_k[0] + w_k[3]) + y * (w_k[1] + w_k[4]) + z * (w_k[2] + w_k[5]);
    qv[t] = qr * (g_q[0] * invs) + b_q[0];
    kv[t] = kr * (g_k[0] * invs) + b_k[0];
    pts4[t] = make_float4(x, y, z, sq);
}

// Pass-kernel decomposition: block = 1024 threads (16 waves), grid = 512.
//   group g = blockIdx>>1 : 64 output points (lane-indexed)
//   half   = blockIdx&1   : which 2048 summed indices
//   wave w : 128 summed indices, uniform loop index -> s_load row data
//   epilogue: LDS reduce 16 waves -> part[half*BN + out]

// ---------------- P1: kd partials -----------------------------------------
__global__ __launch_bounds__(1024, 8)
void p1_kd(const float4* __restrict__ pts4, float* __restrict__ part) {
    int tid = threadIdx.x;
    int wave = __builtin_amdgcn_readfirstlane(tid >> 6);
    int lane = tid & 63;
    int g = blockIdx.x >> 1, half = blockIdx.x & 1;
    int out = g * 64 + lane;
    int b = g >> 6;
    const float4* p = pts4 + (size_t)b * NN;
    float4 fr = pts4[out];
    float acc = 0.f;
    int i0 = half * HALF + wave * RPW;
    #pragma unroll 4
    for (int i = i0; i < i0 + RPW; ++i) {
        float4 fc = p[i];
        float dot = fr.x * fc.x + fr.y * fc.y + fr.z * fc.z;
        float d = fmaf(-2.0f, dot, fr.w) + fc.w;
        acc += __expf(-50.0f * d);
    }
    __shared__ float s_red[16][64];
    s_red[wave][lane] = acc;
    __syncthreads();
    if (tid < 64) {
        float s = 0.f;
        #pragma unroll
        for (int w = 0; w < 16; ++w) s += s_red[w][tid];
        part[half * BN + g * 64 + tid] = s;
    }
}

// ---------------- K2: reduce kd partials + per-batch max -> radius --------
__global__ void k2_radius(const float* __restrict__ part, float* __restrict__ radius) {
    int b = blockIdx.x;
    int t = threadIdx.x;   // 1024
    float kdv[4];
    float mx = -1e30f;
    #pragma unroll
    for (int j = 0; j < 4; ++j) {
        int n = b * NN + j * 1024 + t;
        kdv[j] = part[n] + part[BN + n];
        mx = fmaxf(mx, kdv[j]);
    }
    __shared__ float red[1024];
    red[t] = mx;
    __syncthreads();
    for (int s = 512; s > 0; s >>= 1) {
        if (t < s) red[t] = fmaxf(red[t], red[t + s]);
        __syncthreads();
    }
    float kmax = red[0];
    #pragma unroll
    for (int j = 0; j < 4; ++j) {
        int n = b * NN + j * 1024 + t;
        radius[n] = 0.1f + 0.1f * (kdv[j] / (kmax + 1e-9f));
    }
}

// ---------------- P3: Z partials (row pass) -------------------------------
__global__ __launch_bounds__(1024, 8)
void p3_Z(const float4* __restrict__ pts4, const float* __restrict__ qv,
          const float* __restrict__ kv, const float* __restrict__ radius,
          float* __restrict__ part) {
    int tid = threadIdx.x;
    int wave = __builtin_amdgcn_readfirstlane(tid >> 6);
    int lane = tid & 63;
    int g = blockIdx.x >> 1, half = blockIdx.x & 1;
    int row = g * 64 + lane;
    int b = g >> 6;
    const float4* p = pts4 + (size_t)b * NN;
    const float* kb = kv + (size_t)b * NN;
    float4 fr = pts4[row];
    float qn = qv[row], rad = radius[row];
    float acc = 0.f;
    int i0 = half * HALF + wave * RPW;
    #pragma unroll 4
    for (int i = i0; i < i0 + RPW; ++i) {
        float4 fc = p[i];
        float dot = fr.x * fc.x + fr.y * fc.y + fr.z * fc.z;
        float d = fmaf(-2.0f, dot, fr.w) + fc.w;
        float e = __expf(qn * kb[i]);
        acc += (d < rad) ? e : 0.f;
    }
    __shared__ float s_red[16][64];
    s_red[wave][lane] = acc;
    __syncthreads();
    if (tid < 64) {
        float s = 0.f;
        #pragma unroll
        for (int w = 0; w < 16; ++w) s += s_red[w][tid];
        part[half * BN + g * 64 + tid] = s;
    }
}

// ---------------- R3: Z = sum; aux_a = {q, rad, lnZ, _} -------------------
__global__ void r3_Z(const float* __restrict__ part, const float* __restrict__ qv,
                     const float* __restrict__ radius, float* __restrict__ Z,
                     float4* __restrict__ aux_a) {
    int t = blockIdx.x * blockDim.x + threadIdx.x;
    float s = part[t] + part[BN + t];
    Z[t] = s;
    aux_a[t] = make_float4(qv[t], radius[t], __logf(s), 0.f);
}

// ---------------- P4: colsum partials (col pass) --------------------------
__global__ __launch_bounds__(1024, 8)
void p4_colsum(const float4* __restrict__ pts4, const float4* __restrict__ aux_a,
               const float* __restrict__ kv, float* __restrict__ part) {
    int tid = threadIdx.x;
    int wave = __builtin_amdgcn_readfirstlane(tid >> 6);
    int lane = tid & 63;
    int g = blockIdx.x >> 1, half = blockIdx.x & 1;
    int col = g * 64 + lane;
    int b = g >> 6;
    const float4* p = pts4 + (size_t)b * NN;
    const float4* a = aux_a + (size_t)b * NN;
    float4 fcc = pts4[col];
    float km = kv[col];
    float acc = 0.f;
    int i0 = half * HALF + wave * RPW;
    #pragma unroll 4
    for (int i = i0; i < i0 + RPW; ++i) {
        float4 fr = p[i];
        float4 an = a[i];                       // {q_n, rad_n, lnZ_n, _}
        float dot = fr.x * fcc.x + fr.y * fcc.y + fr.z * fcc.z;
        float d = fmaf(-2.0f, dot, fr.w) + fcc.w;
        float e = __expf(an.x * km - an.z);
        acc += (d < an.y) ? e : 0.f;
    }
    __shared__ float s_red[16][64];
    s_red[wave][lane] = acc;
    __syncthreads();
    if (tid < 64) {
        float s = 0.f;
        #pragma unroll
        for (int w = 0; w < 16; ++w) s += s_red[w][tid];
        part[half * BN + g * 64 + tid] = s;
    }
}

// ---------------- R4: colsum = max(sum,1e-12); kc2 = {k, ln colsum} -------
__global__ void r4_colsum(const float* __restrict__ part, const float* __restrict__ kv,
                          float* __restrict__ colsum, float2* __restrict__ kc2) {
    int t = blockIdx.x * blockDim.x + threadIdx.x;
    float s = fmaxf(part[t] + part[BN + t], 1e-12f);
    colsum[t] = s;
    kc2[t] = make_float2(kv[t], __logf(s));
}

// ---------------- P5: rs partials (row pass) ------------------------------
__global__ __launch_bounds__(1024, 8)
void p5_rs(const float4* __restrict__ pts4, const float* __restrict__ qv,
           const float* __restrict__ radius, const float2* __restrict__ kc2,
           float* __restrict__ part) {
    int tid = threadIdx.x;
    int wave = __builtin_amdgcn_readfirstlane(tid >> 6);
    int lane = tid & 63;
    int g = blockIdx.x >> 1, half = blockIdx.x & 1;
    int row = g * 64 + lane;
    int b = g >> 6;
    const float4* p = pts4 + (size_t)b * NN;
    const float2* kc = kc2 + (size_t)b * NN;
    float4 fr = pts4[row];
    float qn = qv[row], rad = radius[row];
    float acc = 0.f;
    int i0 = half * HALF + wave * RPW;
    #pragma unroll 4
    for (int i = i0; i < i0 + RPW; ++i) {
        float4 fc = p[i];
        float2 km = kc[i];                      // {k_m, ln colsum_m}
        float dot = fr.x * fc.x + fr.y * fc.y + fr.z * fc.z;
        float d = fmaf(-2.0f, dot, fr.w) + fc.w;
        float e = __expf(qn * km.x - km.y);
        acc += (d < rad) ? e : 0.f;
    }
    __shared__ float s_red[16][64];
    s_red[wave][lane] = acc;
    __syncthreads();
    if (tid < 64) {
        float s = 0.f;
        #pragma unroll
        for (int w = 0; w < 16; ++w) s += s_red[w][tid];
        part[half * BN + g * 64 + tid] = s;
    }
}

// ---------------- R5: rs = max(sum/Z, 1e-12); aux_a.w = lnZ + ln rs -------
__global__ void r5_rs(const float* __restrict__ part, const float* __restrict__ Z,
                      float4* __restrict__ aux_a) {
    int t = blockIdx.x * blockDim.x + threadIdx.x;
    float s = part[t] + part[BN + t];
    float rs = fmaxf(s / Z[t], 1e-12f);
    float4 a = aux_a[t];
    a.w = a.z + __logf(rs);
    aux_a[t] = a;
}

// ---------------- P6: smoothed partials (col pass, 3 accumulators) --------
__global__ __launch_bounds__(1024, 8)
void p6_smooth(const float4* __restrict__ pts4, const float4* __restrict__ aux_a,
               const float* __restrict__ kv, float* __restrict__ partx,
               float* __restrict__ party, float* __restrict__ partz) {
    int tid = threadIdx.x;
    int wave = __builtin_amdgcn_readfirstlane(tid >> 6);
    int lane = tid & 63;
    int g = blockIdx.x >> 1, half = blockIdx.x & 1;
    int col = g * 64 + lane;
    int b = g >> 6;
    const float4* p = pts4 + (size_t)b * NN;
    const float4* a = aux_a + (size_t)b * NN;
    float4 fcc = pts4[col];
    float km = kv[col];
    float ax = 0.f, ay = 0.f, az = 0.f;
    int i0 = half * HALF + wave * RPW;
    #pragma unroll 4
    for (int i = i0; i < i0 + RPW; ++i) {
        float4 fr = p[i];
        float4 an = a[i];                       // {q_n, rad_n, lnZ_n, lnZ+ln rs}
        float dot = fr.x * fcc.x + fr.y * fcc.y + fr.z * fcc.z;
        float d = fmaf(-2.0f, dot, fr.w) + fcc.w;
        float w = __expf(an.x * km - an.w);
        w = (d < an.y) ? w : 0.f;
        ax += fr.x * w;
        ay += fr.y * w;
        az += fr.z * w;
    }
    __shared__ float s_rx[16][64];
    __shared__ float s_ry[16][64];
    __shared__ float s_rz[16][64];
    s_rx[wave][lane] = ax;
    s_ry[wave][lane] = ay;
    s_rz[wave][lane] = az;
    __syncthreads();
    if (tid < 64) {
        float sx = 0.f, sy = 0.f, sz = 0.f;
        #pragma unroll
        for (int w = 0; w < 16; ++w) {
            sx += s_rx[w][tid];
            sy += s_ry[w][tid];
            sz += s_rz[w][tid];
        }
        int o = half * BN + g * 64 + tid;
        partx[o] = sx;
        party[o] = sy;
        partz[o] = sz;
    }
}

// ---------------- K7: first-20-by-index in-ball neighbors -----------------
__global__ void k7_pe_idx(const float4* __restrict__ pts4, const float* __restrict__ radius,
                          int* __restrict__ idxg) {
    int wave = threadIdx.x >> 6, lane = threadIdx.x & 63;
    int row = blockIdx.x * 4 + wave;
    int b = row / NN;
    const float4* p = pts4 + (size_t)b * NN;
    float4 fr = pts4[row];
    float rad = radius[row];
    int total = 0;
    int firstm = 0;
    bool have = false;
    unsigned long long lmask = (1ULL << lane) - 1ULL;
    for (int i = 0; i < NN / 64 && total < KNBR; ++i) {
        int m = i * 64 + lane;
        float4 fc = p[m];
        float dot = fr.x * fc.x + fr.y * fc.y + fr.z * fc.z;
        float d = fmaf(-2.0f, dot, fr.w) + fc.w;
        bool inb = !(d > rad);   // dist <= radius
        unsigned long long mask = __ballot(inb);
        if (!have && mask != 0ULL) {
            int src = __ffsll(mask) - 1;
            firstm = __shfl(m, src);
            have = true;
        }
        int pos = total + (int)__popcll(mask & lmask);
        if (inb && pos < KNBR) idxg[(size_t)row * KNBR + pos] = m;
        total += (int)__popcll(mask);
    }
    if (total < KNBR && lane >= total && lane < KNBR)
        idxg[(size_t)row * KNBR + lane] = firstm;
}

// ---------------- K8: fused epilogue (+ smoothed reduce), 8 thr/point -----
__global__ void k8_final(const float* __restrict__ xyz,
                         const float* __restrict__ partx, const float* __restrict__ party,
                         const float* __restrict__ partz, const float* __restrict__ colsum,
                         const int* __restrict__ idxg,
                         const float* __restrict__ w_v, const float* __restrict__ g_v, const float* __restrict__ b_v,
                         const float* __restrict__ w_pe, const float* __restrict__ b_pe,
                         const float* __restrict__ g_pe, const float* __restrict__ bb_pe,
                         const float* __restrict__ w_m1, const float* __restrict__ g_m1, const float* __restrict__ b_m1,
                         const float* __restrict__ w_m2, const float* __restrict__ g_m2, const float* __restrict__ b_m2,
                         const float* __restrict__ w_out, const float* __restrict__ g_out, const float* __restrict__ b_out,
                         float* __restrict__ out) {
    __shared__ float s_pf8[32][9];
    __shared__ float s_pf16[32][17];
    __shared__ float s_g64[32][65];
    int tid = threadIdx.x;
    int ptL = tid >> 3, o = tid & 7;
    int p = blockIdx.x * 32 + ptL;
    int b = p / NN, n = p % NN;
    const float* xb = xyz + (size_t)b * 3 * NN;
    float x = xb[n], y = xb[NN + n], z = xb[2 * NN + n];
    const float invs = rsqrtf(1.0f + 1e-5f);

    // --- phase A: PE 9->8, gelu(bn), max over K; thread = channel o ---
    float w0 = w_pe[o * 9 + 0], w1 = w_pe[o * 9 + 1], w2 = w_pe[o * 9 + 2];
    float w3 = w_pe[o * 9 + 3], w4 = w_pe[o * 9 + 4], w5 = w_pe[o * 9 + 5];
    float w6 = w_pe[o * 9 + 6], w7 = w_pe[o * 9 + 7], w8 = w_pe[o * 9 + 8];
    float bp = b_pe[o], gp = g_pe[o] * invs, bbp = bb_pe[o];
    float mx = -1e30f;
    for (int kk = 0; kk < KNBR; ++kk) {
        int j = idxg[(size_t)p * KNBR + kk];
        float gx = xb[j], gy = xb[NN + j], gz = xb[2 * NN + j];
        float dx = gx - x, dy = gy - y, dz = gz - z;
        float s = w0 * x + w1 * y + w2 * z + w3 * gx + w4 * gy + w5 * gz
                + w6 * dx + w7 * dy + w8 * dz + bp;
        s = gelu_f(s * gp + bbp);
        mx = fmaxf(mx, s);
    }
    s_pf8[ptL][o] = mx;
    __syncthreads();

    // --- phase B: m1 8->16, outputs o and o+8 ---
    #pragma unroll
    for (int rr = 0; rr < 2; ++rr) {
        int r = o + rr * 8;
        const float* w = w_m1 + r * 8;
        float s = 0.f;
        #pragma unroll
        for (int c = 0; c < 8; ++c) s += w[c] * s_pf8[ptL][c];
        s_pf16[ptL][r] = gelu_f(s * (g_m1[r] * invs) + b_m1[r]);
    }
    __syncthreads();

    // --- phase C: m2 16->64 + value conv, gelu(v+pos); channels o*8..o*8+7
    float inv = 1.0f / colsum[p];
    float vx = (partx[p] + partx[BN + p]) * inv - x;
    float vy = (party[p] + party[BN + p]) * inv - y;
    float vz = (partz[p] + partz[BN + p]) * inv - z;
    #pragma unroll
    for (int i = 0; i < 8; ++i) {
        int ch = o * 8 + i;
        const float* wm = w_m2 + ch * 16;
        float pos = 0.f;
        #pragma unroll
        for (int c = 0; c < 16; ++c) pos += wm[c] * s_pf16[ptL][c];
        pos = pos * (g_m2[ch] * invs) + b_m2[ch];
        const float* wv = w_v + ch * 6;
        float vv = wv[0] * vx + wv[1] * vy + wv[2] * vz + wv[3] * x + wv[4] * y + wv[5] * z;
        vv = vv * (g_v[ch] * invs) + b_v[ch];
        s_g64[ptL][ch] = gelu_f(vv + pos);
    }
    __syncthreads();

    // --- phase D: out conv 64->32 + BN; outputs o*4..o*4+3 ---
    #pragma unroll
    for (int i = 0; i < 4; ++i) {
        int ch = o * 4 + i;
        const float* w = w_out + ch * 64;
        float s = 0.f;
        #pragma unroll
        for (int c = 0; c < 64; ++c) s += w[c] * s_g64[ptL][c];
        out[((size_t)b * 32 + ch) * NN + n] = s * (g_out[ch] * invs) + b_out[ch];
    }
}

extern "C" void kernel_launch(void* const* d_in, const int* in_sizes, int n_in,
                              void* d_out, int out_size, void* d_ws, size_t ws_size,
                              hipStream_t stream) {
    const float* xyz  = (const float*)d_in[0];
    const float* w_q  = (const float*)d_in[1];
    const float* g_q  = (const float*)d_in[2];
    const float* b_q  = (const float*)d_in[3];
    const float* w_k  = (const float*)d_in[4];
    const float* g_k  = (const float*)d_in[5];
    const float* b_k  = (const float*)d_in[6];
    const float* w_v  = (const float*)d_in[7];
    const float* g_v  = (const float*)d_in[8];
    const float* b_v  = (const float*)d_in[9];
    const float* w_pe = (const float*)d_in[10];
    const float* b_pe = (const float*)d_in[11];
    const float* g_pe = (const float*)d_in[12];
    const float* bb_pe= (const float*)d_in[13];
    const float* w_m1 = (const float*)d_in[14];
    const float* g_m1 = (const float*)d_in[15];
    const float* b_m1 = (const float*)d_in[16];
    const float* w_m2 = (const float*)d_in[17];
    const float* g_m2 = (const float*)d_in[18];
    const float* b_m2 = (const float*)d_in[19];
    const float* w_out= (const float*)d_in[20];
    const float* g_out= (const float*)d_in[21];
    const float* b_out= (const float*)d_in[22];

    float* ws = (float*)d_ws;
    float*  qv       = ws;                               // BN
    float*  kv       = ws + (size_t)1 * BN;              // BN
    float4* pts4     = (float4*)(ws + (size_t)2 * BN);   // 4BN
    float*  radius   = ws + (size_t)6 * BN;              // BN
    float*  Zv       = ws + (size_t)7 * BN;              // BN
    float*  colsum   = ws + (size_t)8 * BN;              // BN
    float4* aux_a    = (float4*)(ws + (size_t)9 * BN);   // 4BN
    float2* kc2      = (float2*)(ws + (size_t)13 * BN);  // 2BN
    int*    idxg     = (int*)(ws + (size_t)15 * BN);     // 20BN
    float*  part_s   = ws + (size_t)35 * BN;             // 2BN (reused by p1/p3/p4/p5)
    float*  partx    = ws + (size_t)37 * BN;             // 2BN
    float*  party    = ws + (size_t)39 * BN;             // 2BN
    float*  partz    = ws + (size_t)41 * BN;             // 2BN

    const int PB = (BN / 64) * 2;   // 512 blocks of 1024 threads

    k0_prep<<<BN / 256, 256, 0, stream>>>(xyz, w_q, g_q, b_q, w_k, g_k, b_k, qv, kv, pts4);
    p1_kd<<<PB, 1024, 0, stream>>>(pts4, part_s);
    k2_radius<<<BB, 1024, 0, stream>>>(part_s, radius);
    p3_Z<<<PB, 1024, 0, stream>>>(pts4, qv, kv, radius, part_s);
    r3_Z<<<BN / 256, 256, 0, stream>>>(part_s, qv, radius, Zv, aux_a);
    p4_colsum<<<PB, 1024, 0, stream>>>(pts4, aux_a, kv, part_s);
    r4_colsum<<<BN / 256, 256, 0, stream>>>(part_s, kv, colsum, kc2);
    p5_rs<<<PB, 1024, 0, stream>>>(pts4, qv, radius, kc2, part_s);
    r5_rs<<<BN / 256, 256, 0, stream>>>(part_s, Zv, aux_a);
    p6_smooth<<<PB, 1024, 0, stream>>>(pts4, aux_a, kv, partx, party, partz);
    k7_pe_idx<<<BN / 4, 256, 0, stream>>>(pts4, radius, idxg);
    k8_final<<<BN / 32, 256, 0, stream>>>(xyz, partx, party, partz, colsum, idxg,
                                          w_v, g_v, b_v,
                                          w_pe, b_pe, g_pe, bb_pe,
                                          w_m1, g_m1, b_m1,
                                          w_m2, g_m2, b_m2,
                                          w_out, g_out, b_out,
                                          (float*)d_out);
}